// Round 1
// baseline (1151.591 us; speedup 1.0000x reference)
//
#include <hip/hip_runtime.h>
#include <math.h>

constexpr int kNodes = 50000;
constexpr int kEdges = 600000;
constexpr int kF     = 128;
constexpr int kNPB   = 64;   // nodes per block in linear_tanh

// ---------------------------------------------------------------------------
// Kernel 0: transpose W [o][k] -> Wt [k][o] in d_ws so linear_tanh can stage
// it into LDS with fully coalesced float4 loads and conflict-free b128 reads.
__global__ __launch_bounds__(256) void transpose_w(const float* __restrict__ W,
                                                   float* __restrict__ Wt) {
    int gid = blockIdx.x * 256 + threadIdx.x;   // 0..16383
    int k = gid >> 7;
    int o = gid & (kF - 1);
    Wt[gid] = W[o * kF + k];
}

// ---------------------------------------------------------------------------
// Kernel 1: scatter-add  agg[dst[e]] += feature[src[e]]
// 32 threads per edge, float4 gather, 4 fp32 atomics per thread.
__global__ __launch_bounds__(256) void scatter_add(const float* __restrict__ feature,
                                                   const int* __restrict__ src,
                                                   const int* __restrict__ dst,
                                                   float* __restrict__ agg) {
    int gid = blockIdx.x * 256 + threadIdx.x;
    int e = gid >> 5;            // edge id (grid sized exactly: no bounds check)
    int c = (gid & 31) << 2;     // float offset within the 128-wide row
    int s = src[e];
    int d = dst[e];
    float4 v = *reinterpret_cast<const float4*>(feature + (size_t)s * kF + c);
    float* p = agg + (size_t)d * kF + c;
    atomicAdd(p + 0, v.x);
    atomicAdd(p + 1, v.y);
    atomicAdd(p + 2, v.z);
    atomicAdd(p + 3, v.w);
}

// ---------------------------------------------------------------------------
// Kernel 2: out[n] = tanh(agg[n] @ W^T + b), in place on `inout`.
// Each block: 64 node rows staged to LDS, Wt (transposed W) staged to LDS.
// Thread micro-tile: 8 nodes x 4 outputs (acc[8][4]), k unrolled by 4.
__global__ __launch_bounds__(256) void linear_tanh(float* __restrict__ inout,
                                                   const float* __restrict__ Wt,
                                                   const float* __restrict__ bias) {
    __shared__ float sWt[kF * kF];      // sWt[k*128 + o] = W[o][k]   (64 KB)
    __shared__ float sAgg[kNPB * kF];   // 32 KB
    __shared__ float sB[kF];

    const int t  = threadIdx.x;
    const int n0 = blockIdx.x * kNPB;

    // Stage Wt: straight coalesced float4 copy, conflict-free LDS writes.
    for (int i = t * 4; i < kF * kF; i += 256 * 4) {
        *reinterpret_cast<float4*>(&sWt[i]) =
            *reinterpret_cast<const float4*>(Wt + i);
    }
    if (t < kF) sB[t] = bias[t];

    // Stage this block's agg rows (read-before-overwrite => in-place is safe).
    const int rows = min(kNPB, kNodes - n0);
    for (int i = t * 4; i < rows * kF; i += 256 * 4) {
        *reinterpret_cast<float4*>(&sAgg[i]) =
            *reinterpret_cast<const float4*>(inout + (size_t)n0 * kF + i);
    }
    __syncthreads();

    const int tn = t >> 5;        // 0..7  -> node sub-block
    const int to = t & 31;        // 0..31 -> output group, o = to*4 + j
    const int nb = tn * 8;        // 8 nodes per thread

    float acc[8][4];
#pragma unroll
    for (int n = 0; n < 8; ++n)
#pragma unroll
        for (int j = 0; j < 4; ++j) acc[n][j] = 0.0f;

    for (int k = 0; k < kF; k += 4) {
        // wt[i] = (W[4to+0][k+i], W[4to+1][k+i], W[4to+2][k+i], W[4to+3][k+i])
        float4 wt[4];
#pragma unroll
        for (int i = 0; i < 4; ++i)
            wt[i] = *reinterpret_cast<const float4*>(&sWt[(k + i) * kF + to * 4]);
#pragma unroll
        for (int n = 0; n < 8; ++n) {
            float4 av = *reinterpret_cast<const float4*>(&sAgg[(nb + n) * kF + k]);
#pragma unroll
            for (int j = 0; j < 4; ++j) {
                float* wj0 = reinterpret_cast<float*>(&wt[0]);
                float* wj1 = reinterpret_cast<float*>(&wt[1]);
                float* wj2 = reinterpret_cast<float*>(&wt[2]);
                float* wj3 = reinterpret_cast<float*>(&wt[3]);
                acc[n][j] += av.x * wj0[j];
                acc[n][j] += av.y * wj1[j];
                acc[n][j] += av.z * wj2[j];
                acc[n][j] += av.w * wj3[j];
            }
        }
    }

    const float b0 = sB[to * 4 + 0];
    const float b1 = sB[to * 4 + 1];
    const float b2 = sB[to * 4 + 2];
    const float b3 = sB[to * 4 + 3];

#pragma unroll
    for (int n = 0; n < 8; ++n) {
        int node = n0 + nb + n;
        if (node < kNodes) {
            float4 r;
            // fast tanh: 1 - 2/(e^{2x}+1); exact saturation at +-inf, ~1e-6 rel err
            r.x = 1.0f - 2.0f / (__expf(2.0f * (acc[n][0] + b0)) + 1.0f);
            r.y = 1.0f - 2.0f / (__expf(2.0f * (acc[n][1] + b1)) + 1.0f);
            r.z = 1.0f - 2.0f / (__expf(2.0f * (acc[n][2] + b2)) + 1.0f);
            r.w = 1.0f - 2.0f / (__expf(2.0f * (acc[n][3] + b3)) + 1.0f);
            *reinterpret_cast<float4*>(inout + (size_t)node * kF + to * 4) = r;
        }
    }
}

// ---------------------------------------------------------------------------
extern "C" void kernel_launch(void* const* d_in, const int* in_sizes, int n_in,
                              void* d_out, int out_size, void* d_ws, size_t ws_size,
                              hipStream_t stream) {
    const float* feature = (const float*)d_in[0];
    const float* W       = (const float*)d_in[1];
    const float* b       = (const float*)d_in[2];
    const int*   src     = (const int*)d_in[3];
    const int*   dst     = (const int*)d_in[4];
    float* out = (float*)d_out;
    float* Wt  = (float*)d_ws;   // 64 KB scratch for transposed W

    // agg accumulates in place in d_out (harness poisons it -> zero first)
    hipMemsetAsync(d_out, 0, (size_t)kNodes * kF * sizeof(float), stream);

    transpose_w<<<(kF * kF) / 256, 256, 0, stream>>>(W, Wt);
    scatter_add<<<(kEdges * 32) / 256, 256, 0, stream>>>(feature, src, dst, out);
    linear_tanh<<<(kNodes + kNPB - 1) / kNPB, 256, 0, stream>>>(out, Wt, b);
}

// Round 2
// 366.659 us; speedup vs baseline: 3.1408x; 3.1408x over previous
//
#include <hip/hip_runtime.h>
#include <math.h>

constexpr int kNodes = 50000;
constexpr int kEdges = 600000;
constexpr int kF     = 128;
constexpr int kNPB   = 64;   // nodes per block in linear_tanh

// ---------------------------------------------------------------------------
// Kernel 0: transpose W [o][k] -> Wt [k][o] for conflict-free LDS staging.
__global__ __launch_bounds__(256) void transpose_w(const float* __restrict__ W,
                                                   float* __restrict__ Wt) {
    int gid = blockIdx.x * 256 + threadIdx.x;   // 0..16383
    int k = gid >> 7;
    int o = gid & (kF - 1);
    Wt[gid] = W[o * kF + k];
}

// ---------------------------------------------------------------------------
// CSR build: histogram of dst, exclusive scan, bucket fill with src ids.
__global__ __launch_bounds__(256) void histogram(const int* __restrict__ dst,
                                                 int* __restrict__ deg) {
    int e = blockIdx.x * 256 + threadIdx.x;
    if (e < kEdges) atomicAdd(&deg[dst[e]], 1);
}

__global__ __launch_bounds__(1024) void scan_offsets(const int* __restrict__ deg,
                                                     int* __restrict__ offs,
                                                     int* __restrict__ cursor) {
    __shared__ int partial[1024];
    const int t = threadIdx.x;
    const int per = (kNodes + 1023) / 1024;   // 49
    const int base = t * per;

    int sum = 0;
    for (int i = 0; i < per; ++i) {
        int idx = base + i;
        if (idx < kNodes) sum += deg[idx];
    }
    partial[t] = sum;
    __syncthreads();
    // inclusive scan of per-thread partials
    for (int off = 1; off < 1024; off <<= 1) {
        int v = 0;
        if (t >= off) v = partial[t - off];
        __syncthreads();
        if (t >= off) partial[t] += v;
        __syncthreads();
    }
    int run = (t == 0) ? 0 : partial[t - 1];
    for (int i = 0; i < per; ++i) {
        int idx = base + i;
        if (idx < kNodes) {
            offs[idx]   = run;
            cursor[idx] = run;
            run += deg[idx];
        }
    }
    if (t == 1023) offs[kNodes] = run;   // == kEdges
}

__global__ __launch_bounds__(256) void bucket_fill(const int* __restrict__ src,
                                                   const int* __restrict__ dst,
                                                   int* __restrict__ cursor,
                                                   int* __restrict__ bucket) {
    int e = blockIdx.x * 256 + threadIdx.x;
    if (e < kEdges) {
        int p = atomicAdd(&cursor[dst[e]], 1);
        bucket[p] = src[e];
    }
}

// ---------------------------------------------------------------------------
// Kernel 1': one wave per node. Lane l accumulates float2 columns [2l, 2l+1]
// over all incoming edges. Edge ids loaded once per 64-chunk, broadcast via
// __shfl. Zero atomics; coalesced 512B row reads (cache-resident feature).
__global__ __launch_bounds__(256) void gather_sum(const float* __restrict__ feature,
                                                  const int* __restrict__ bucket,
                                                  const int* __restrict__ offs,
                                                  float* __restrict__ agg) {
    const int wave = (blockIdx.x * 256 + threadIdx.x) >> 6;
    const int lane = threadIdx.x & 63;
    if (wave >= kNodes) return;

    const int beg = offs[wave];
    const int end = offs[wave + 1];
    const float2* f2 = reinterpret_cast<const float2*>(feature);

    float2 acc = make_float2(0.0f, 0.0f);
    for (int j0 = beg; j0 < end; j0 += 64) {
        const int cnt = min(64, end - j0);
        int sid = (lane < cnt) ? bucket[j0 + lane] : 0;
#pragma unroll 4
        for (int j = 0; j < cnt; ++j) {
            int s = __shfl(sid, j);
            float2 v = f2[(size_t)s * 64 + lane];
            acc.x += v.x;
            acc.y += v.y;
        }
    }
    reinterpret_cast<float2*>(agg)[(size_t)wave * 64 + lane] = acc;
}

// ---------------------------------------------------------------------------
// Kernel 2: out[n] = tanh(agg[n] @ W^T + b), in place on `inout`.
__global__ __launch_bounds__(256) void linear_tanh(float* __restrict__ inout,
                                                   const float* __restrict__ Wt,
                                                   const float* __restrict__ bias) {
    __shared__ float sWt[kF * kF];      // sWt[k*128 + o] = W[o][k]   (64 KB)
    __shared__ float sAgg[kNPB * kF];   // 32 KB
    __shared__ float sB[kF];

    const int t  = threadIdx.x;
    const int n0 = blockIdx.x * kNPB;

    for (int i = t * 4; i < kF * kF; i += 256 * 4) {
        *reinterpret_cast<float4*>(&sWt[i]) =
            *reinterpret_cast<const float4*>(Wt + i);
    }
    if (t < kF) sB[t] = bias[t];

    const int rows = min(kNPB, kNodes - n0);
    for (int i = t * 4; i < rows * kF; i += 256 * 4) {
        *reinterpret_cast<float4*>(&sAgg[i]) =
            *reinterpret_cast<const float4*>(inout + (size_t)n0 * kF + i);
    }
    __syncthreads();

    const int tn = t >> 5;        // 0..7
    const int to = t & 31;        // 0..31
    const int nb = tn * 8;

    float acc[8][4];
#pragma unroll
    for (int n = 0; n < 8; ++n)
#pragma unroll
        for (int j = 0; j < 4; ++j) acc[n][j] = 0.0f;

    for (int k = 0; k < kF; k += 4) {
        float4 wt[4];
#pragma unroll
        for (int i = 0; i < 4; ++i)
            wt[i] = *reinterpret_cast<const float4*>(&sWt[(k + i) * kF + to * 4]);
#pragma unroll
        for (int n = 0; n < 8; ++n) {
            float4 av = *reinterpret_cast<const float4*>(&sAgg[(nb + n) * kF + k]);
#pragma unroll
            for (int j = 0; j < 4; ++j) {
                float* wj0 = reinterpret_cast<float*>(&wt[0]);
                float* wj1 = reinterpret_cast<float*>(&wt[1]);
                float* wj2 = reinterpret_cast<float*>(&wt[2]);
                float* wj3 = reinterpret_cast<float*>(&wt[3]);
                acc[n][j] += av.x * wj0[j];
                acc[n][j] += av.y * wj1[j];
                acc[n][j] += av.z * wj2[j];
                acc[n][j] += av.w * wj3[j];
            }
        }
    }

    const float b0 = sB[to * 4 + 0];
    const float b1 = sB[to * 4 + 1];
    const float b2 = sB[to * 4 + 2];
    const float b3 = sB[to * 4 + 3];

#pragma unroll
    for (int n = 0; n < 8; ++n) {
        int node = n0 + nb + n;
        if (node < kNodes) {
            float4 r;
            r.x = 1.0f - 2.0f / (__expf(2.0f * (acc[n][0] + b0)) + 1.0f);
            r.y = 1.0f - 2.0f / (__expf(2.0f * (acc[n][1] + b1)) + 1.0f);
            r.z = 1.0f - 2.0f / (__expf(2.0f * (acc[n][2] + b2)) + 1.0f);
            r.w = 1.0f - 2.0f / (__expf(2.0f * (acc[n][3] + b3)) + 1.0f);
            *reinterpret_cast<float4*>(inout + (size_t)node * kF + to * 4) = r;
        }
    }
}

// ---------------------------------------------------------------------------
extern "C" void kernel_launch(void* const* d_in, const int* in_sizes, int n_in,
                              void* d_out, int out_size, void* d_ws, size_t ws_size,
                              hipStream_t stream) {
    const float* feature = (const float*)d_in[0];
    const float* W       = (const float*)d_in[1];
    const float* b       = (const float*)d_in[2];
    const int*   src     = (const int*)d_in[3];
    const int*   dst     = (const int*)d_in[4];
    float* out = (float*)d_out;

    // workspace layout (16B-aligned chunks)
    char* ws = (char*)d_ws;
    float* Wt     = (float*)(ws);                       //  64 KB
    int*   deg    = (int*)(ws + 65536);                 // 200 KB
    int*   offs   = (int*)(ws + 65536 + 200000);        // 200 KB (+4)
    int*   cursor = (int*)(ws + 65536 + 400016);        // 200 KB
    int*   bucket = (int*)(ws + 65536 + 600016);        // 2.4 MB

    hipMemsetAsync(deg, 0, kNodes * sizeof(int), stream);

    transpose_w<<<(kF * kF) / 256, 256, 0, stream>>>(W, Wt);
    histogram<<<(kEdges + 255) / 256, 256, 0, stream>>>(dst, deg);
    scan_offsets<<<1, 1024, 0, stream>>>(deg, offs, cursor);
    bucket_fill<<<(kEdges + 255) / 256, 256, 0, stream>>>(src, dst, cursor, bucket);

    // one wave per node: 50000 waves, 4 waves/block
    gather_sum<<<(kNodes + 3) / 4, 256, 0, stream>>>(feature, bucket, offs, out);

    linear_tanh<<<(kNodes + kNPB - 1) / kNPB, 256, 0, stream>>>(out, Wt, b);
}

// Round 3
// 254.293 us; speedup vs baseline: 4.5286x; 1.4419x over previous
//
#include <hip/hip_runtime.h>
#include <math.h>

constexpr int kNodes = 50000;
constexpr int kEdges = 600000;
constexpr int kF     = 128;
constexpr int kNPB   = 64;                       // nodes per block in linear_tanh
constexpr int kScanB = (kNodes + 255) / 256;     // 196 scan blocks

// ---------------------------------------------------------------------------
// Kernel 0: transpose W [o][k] -> Wt [k][o] for conflict-free LDS staging.
__global__ __launch_bounds__(256) void transpose_w(const float* __restrict__ W,
                                                   float* __restrict__ Wt) {
    int gid = blockIdx.x * 256 + threadIdx.x;   // 0..16383
    int k = gid >> 7;
    int o = gid & (kF - 1);
    Wt[gid] = W[o * kF + k];
}

// ---------------------------------------------------------------------------
// CSR build: histogram of dst, hierarchical exclusive scan, bucket fill.
__global__ __launch_bounds__(256) void histogram(const int* __restrict__ dst,
                                                 int* __restrict__ deg) {
    int e = blockIdx.x * 256 + threadIdx.x;
    if (e < kEdges) atomicAdd(&deg[dst[e]], 1);
}

// Phase A: per-block sums of 256 degrees (coalesced).
__global__ __launch_bounds__(256) void block_sums(const int* __restrict__ deg,
                                                  int* __restrict__ bsum) {
    __shared__ int s[256];
    const int t = threadIdx.x;
    int gid = blockIdx.x * 256 + t;
    s[t] = (gid < kNodes) ? deg[gid] : 0;
    __syncthreads();
    for (int off = 128; off > 0; off >>= 1) {
        if (t < off) s[t] += s[t + off];
        __syncthreads();
    }
    if (t == 0) bsum[blockIdx.x] = s[0];
}

// Phase B: exclusive scan of the 196 block sums (single tiny block).
__global__ __launch_bounds__(256) void scan_bsums(const int* __restrict__ bsum,
                                                  int* __restrict__ bpre) {
    __shared__ int s[256];
    const int t = threadIdx.x;
    int v = (t < kScanB) ? bsum[t] : 0;
    s[t] = v;
    __syncthreads();
    for (int off = 1; off < 256; off <<= 1) {
        int u = (t >= off) ? s[t - off] : 0;
        __syncthreads();
        s[t] += u;
        __syncthreads();
    }
    if (t < kScanB) bpre[t] = s[t] - v;   // exclusive
}

// Phase C: block-local inclusive scan + block prefix -> exclusive offsets.
__global__ __launch_bounds__(256) void scan_final(const int* __restrict__ deg,
                                                  const int* __restrict__ bpre,
                                                  int* __restrict__ offs,
                                                  int* __restrict__ cursor) {
    __shared__ int s[256];
    const int t = threadIdx.x;
    int gid = blockIdx.x * 256 + t;
    int v = (gid < kNodes) ? deg[gid] : 0;
    s[t] = v;
    __syncthreads();
    for (int off = 1; off < 256; off <<= 1) {
        int u = (t >= off) ? s[t - off] : 0;
        __syncthreads();
        s[t] += u;
        __syncthreads();
    }
    if (gid < kNodes) {
        int ex = bpre[blockIdx.x] + s[t] - v;
        offs[gid]   = ex;
        cursor[gid] = ex;
    }
    if (gid == 0) offs[kNodes] = kEdges;   // total is a compile-time constant
}

__global__ __launch_bounds__(256) void bucket_fill(const int* __restrict__ src,
                                                   const int* __restrict__ dst,
                                                   int* __restrict__ cursor,
                                                   int* __restrict__ bucket) {
    int e = blockIdx.x * 256 + threadIdx.x;
    if (e < kEdges) {
        int p = atomicAdd(&cursor[dst[e]], 1);
        bucket[p] = src[e];
    }
}

// ---------------------------------------------------------------------------
// Kernel 1': one wave per node. Lane l accumulates float2 columns [2l, 2l+1]
// over all incoming edges. Edge ids loaded once per 64-chunk, broadcast via
// __shfl. Zero atomics; coalesced 512B row reads (cache-resident feature).
__global__ __launch_bounds__(256) void gather_sum(const float* __restrict__ feature,
                                                  const int* __restrict__ bucket,
                                                  const int* __restrict__ offs,
                                                  float* __restrict__ agg) {
    const int wave = (blockIdx.x * 256 + threadIdx.x) >> 6;
    const int lane = threadIdx.x & 63;
    if (wave >= kNodes) return;

    const int beg = offs[wave];
    const int end = offs[wave + 1];
    const float2* f2 = reinterpret_cast<const float2*>(feature);

    float2 acc = make_float2(0.0f, 0.0f);
    for (int j0 = beg; j0 < end; j0 += 64) {
        const int cnt = min(64, end - j0);
        int sid = (lane < cnt) ? bucket[j0 + lane] : 0;
#pragma unroll 4
        for (int j = 0; j < cnt; ++j) {
            int s = __shfl(sid, j);
            float2 v = f2[(size_t)s * 64 + lane];
            acc.x += v.x;
            acc.y += v.y;
        }
    }
    reinterpret_cast<float2*>(agg)[(size_t)wave * 64 + lane] = acc;
}

// ---------------------------------------------------------------------------
// Kernel 2: out[n] = tanh(agg[n] @ W^T + b), in place on `inout`.
__global__ __launch_bounds__(256) void linear_tanh(float* __restrict__ inout,
                                                   const float* __restrict__ Wt,
                                                   const float* __restrict__ bias) {
    __shared__ float sWt[kF * kF];      // sWt[k*128 + o] = W[o][k]   (64 KB)
    __shared__ float sAgg[kNPB * kF];   // 32 KB
    __shared__ float sB[kF];

    const int t  = threadIdx.x;
    const int n0 = blockIdx.x * kNPB;

    for (int i = t * 4; i < kF * kF; i += 256 * 4) {
        *reinterpret_cast<float4*>(&sWt[i]) =
            *reinterpret_cast<const float4*>(Wt + i);
    }
    if (t < kF) sB[t] = bias[t];

    const int rows = min(kNPB, kNodes - n0);
    for (int i = t * 4; i < rows * kF; i += 256 * 4) {
        *reinterpret_cast<float4*>(&sAgg[i]) =
            *reinterpret_cast<const float4*>(inout + (size_t)n0 * kF + i);
    }
    __syncthreads();

    const int tn = t >> 5;        // 0..7
    const int to = t & 31;        // 0..31
    const int nb = tn * 8;

    float acc[8][4];
#pragma unroll
    for (int n = 0; n < 8; ++n)
#pragma unroll
        for (int j = 0; j < 4; ++j) acc[n][j] = 0.0f;

    for (int k = 0; k < kF; k += 4) {
        float4 wt[4];
#pragma unroll
        for (int i = 0; i < 4; ++i)
            wt[i] = *reinterpret_cast<const float4*>(&sWt[(k + i) * kF + to * 4]);
#pragma unroll
        for (int n = 0; n < 8; ++n) {
            float4 av = *reinterpret_cast<const float4*>(&sAgg[(nb + n) * kF + k]);
#pragma unroll
            for (int j = 0; j < 4; ++j) {
                float* wj0 = reinterpret_cast<float*>(&wt[0]);
                float* wj1 = reinterpret_cast<float*>(&wt[1]);
                float* wj2 = reinterpret_cast<float*>(&wt[2]);
                float* wj3 = reinterpret_cast<float*>(&wt[3]);
                acc[n][j] += av.x * wj0[j];
                acc[n][j] += av.y * wj1[j];
                acc[n][j] += av.z * wj2[j];
                acc[n][j] += av.w * wj3[j];
            }
        }
    }

    const float b0 = sB[to * 4 + 0];
    const float b1 = sB[to * 4 + 1];
    const float b2 = sB[to * 4 + 2];
    const float b3 = sB[to * 4 + 3];

#pragma unroll
    for (int n = 0; n < 8; ++n) {
        int node = n0 + nb + n;
        if (node < kNodes) {
            float4 r;
            r.x = 1.0f - 2.0f / (__expf(2.0f * (acc[n][0] + b0)) + 1.0f);
            r.y = 1.0f - 2.0f / (__expf(2.0f * (acc[n][1] + b1)) + 1.0f);
            r.z = 1.0f - 2.0f / (__expf(2.0f * (acc[n][2] + b2)) + 1.0f);
            r.w = 1.0f - 2.0f / (__expf(2.0f * (acc[n][3] + b3)) + 1.0f);
            *reinterpret_cast<float4*>(inout + (size_t)node * kF + to * 4) = r;
        }
    }
}

// ---------------------------------------------------------------------------
extern "C" void kernel_launch(void* const* d_in, const int* in_sizes, int n_in,
                              void* d_out, int out_size, void* d_ws, size_t ws_size,
                              hipStream_t stream) {
    const float* feature = (const float*)d_in[0];
    const float* W       = (const float*)d_in[1];
    const float* b       = (const float*)d_in[2];
    const int*   src     = (const int*)d_in[3];
    const int*   dst     = (const int*)d_in[4];
    float* out = (float*)d_out;

    // workspace layout (16B-aligned chunks)
    char* ws = (char*)d_ws;
    float* Wt     = (float*)(ws);                       //  64 KB
    int*   deg    = (int*)(ws + 65536);                 // 200 KB
    int*   offs   = (int*)(ws + 65536 + 200016);        // 200 KB (+4)
    int*   cursor = (int*)(ws + 65536 + 400032);        // 200 KB
    int*   bucket = (int*)(ws + 65536 + 600048);        // 2.4 MB
    int*   bsum   = (int*)(ws + 65536 + 600048 + 2400000);        // 784 B
    int*   bpre   = (int*)(ws + 65536 + 600048 + 2400000 + 800);  // 784 B

    hipMemsetAsync(deg, 0, kNodes * sizeof(int), stream);

    transpose_w<<<(kF * kF) / 256, 256, 0, stream>>>(W, Wt);
    histogram<<<(kEdges + 255) / 256, 256, 0, stream>>>(dst, deg);
    block_sums<<<kScanB, 256, 0, stream>>>(deg, bsum);
    scan_bsums<<<1, 256, 0, stream>>>(bsum, bpre);
    scan_final<<<kScanB, 256, 0, stream>>>(deg, bpre, offs, cursor);
    bucket_fill<<<(kEdges + 255) / 256, 256, 0, stream>>>(src, dst, cursor, bucket);

    // one wave per node: 50000 waves, 4 waves/block
    gather_sum<<<(kNodes + 3) / 4, 256, 0, stream>>>(feature, bucket, offs, out);

    linear_tanh<<<(kNodes + kNPB - 1) / kNPB, 256, 0, stream>>>(out, Wt, b);
}

// Round 4
// 224.220 us; speedup vs baseline: 5.1360x; 1.1341x over previous
//
#include <hip/hip_runtime.h>
#include <math.h>

constexpr int kNodes = 50000;
constexpr int kEdges = 600000;
constexpr int kF     = 128;
constexpr int kNPB   = 64;                       // nodes per block in linear_tanh
constexpr int kScanB = (kNodes + 255) / 256;     // 196 scan blocks

// ---------------------------------------------------------------------------
// Kernel 0: prep — transpose W [o][k] -> Wt [k][o] AND zero the degree array
// (replaces a separate hipMemsetAsync dispatch).
__global__ __launch_bounds__(256) void prep(const float* __restrict__ W,
                                            float* __restrict__ Wt,
                                            int* __restrict__ deg) {
    int gid = blockIdx.x * 256 + threadIdx.x;    // grid covers 50176
    if (gid < kF * kF) {
        int k = gid >> 7;
        int o = gid & (kF - 1);
        Wt[gid] = W[o * kF + k];
    }
    if (gid < kNodes) deg[gid] = 0;
}

// ---------------------------------------------------------------------------
// CSR build: histogram of dst, hierarchical exclusive scan, bucket fill.
__global__ __launch_bounds__(256) void histogram(const int* __restrict__ dst,
                                                 int* __restrict__ deg) {
    int e = blockIdx.x * 256 + threadIdx.x;
    if (e < kEdges) atomicAdd(&deg[dst[e]], 1);
}

// Phase A: per-block sums of 256 degrees (coalesced).
__global__ __launch_bounds__(256) void block_sums(const int* __restrict__ deg,
                                                  int* __restrict__ bsum) {
    __shared__ int s[256];
    const int t = threadIdx.x;
    int gid = blockIdx.x * 256 + t;
    s[t] = (gid < kNodes) ? deg[gid] : 0;
    __syncthreads();
    for (int off = 128; off > 0; off >>= 1) {
        if (t < off) s[t] += s[t + off];
        __syncthreads();
    }
    if (t == 0) bsum[blockIdx.x] = s[0];
}

// Phase B+C fused: each block scans the 196 bsums itself (tiny), then does its
// block-local inclusive scan of deg and writes exclusive offsets + cursor.
__global__ __launch_bounds__(256) void scan_final(const int* __restrict__ deg,
                                                  const int* __restrict__ bsum,
                                                  int* __restrict__ offs,
                                                  int* __restrict__ cursor) {
    __shared__ int s[256];
    const int t = threadIdx.x;
    const int b = blockIdx.x;

    // scan the block sums (196 values) to get this block's prefix
    s[t] = (t < kScanB) ? bsum[t] : 0;
    __syncthreads();
    for (int off = 1; off < 256; off <<= 1) {
        int u = (t >= off) ? s[t - off] : 0;
        __syncthreads();
        s[t] += u;
        __syncthreads();
    }
    const int bpre = (b == 0) ? 0 : s[b - 1];   // exclusive prefix of block b
    __syncthreads();

    // block-local inclusive scan of deg
    int gid = b * 256 + t;
    int v = (gid < kNodes) ? deg[gid] : 0;
    s[t] = v;
    __syncthreads();
    for (int off = 1; off < 256; off <<= 1) {
        int u = (t >= off) ? s[t - off] : 0;
        __syncthreads();
        s[t] += u;
        __syncthreads();
    }
    if (gid < kNodes) {
        int ex = bpre + s[t] - v;
        offs[gid]   = ex;
        cursor[gid] = ex;
    }
    if (gid == 0) offs[kNodes] = kEdges;   // total is a compile-time constant
}

__global__ __launch_bounds__(256) void bucket_fill(const int* __restrict__ src,
                                                   const int* __restrict__ dst,
                                                   int* __restrict__ cursor,
                                                   int* __restrict__ bucket) {
    int e = blockIdx.x * 256 + threadIdx.x;
    if (e < kEdges) {
        int p = atomicAdd(&cursor[dst[e]], 1);
        bucket[p] = src[e];
    }
}

// ---------------------------------------------------------------------------
// Kernel 1': one wave per node. Lane l accumulates float2 columns [2l, 2l+1]
// over all incoming edges. Edge ids loaded once per 64-chunk, broadcast via
// __shfl. Zero atomics; coalesced 512B row reads (cache-resident feature).
__global__ __launch_bounds__(256) void gather_sum(const float* __restrict__ feature,
                                                  const int* __restrict__ bucket,
                                                  const int* __restrict__ offs,
                                                  float* __restrict__ agg) {
    const int wave = (blockIdx.x * 256 + threadIdx.x) >> 6;
    const int lane = threadIdx.x & 63;
    if (wave >= kNodes) return;

    const int beg = offs[wave];
    const int end = offs[wave + 1];
    const float2* f2 = reinterpret_cast<const float2*>(feature);

    float2 acc = make_float2(0.0f, 0.0f);
    for (int j0 = beg; j0 < end; j0 += 64) {
        const int cnt = min(64, end - j0);
        int sid = (lane < cnt) ? bucket[j0 + lane] : 0;
#pragma unroll 4
        for (int j = 0; j < cnt; ++j) {
            int s = __shfl(sid, j);
            float2 v = f2[(size_t)s * 64 + lane];
            acc.x += v.x;
            acc.y += v.y;
        }
    }
    reinterpret_cast<float2*>(agg)[(size_t)wave * 64 + lane] = acc;
}

// ---------------------------------------------------------------------------
// Kernel 2: out[n] = tanh(agg[n] @ W^T + b), in place on `inout`.
// v2: Wt read straight from global (L1/L2-resident, wave-broadcast rows) —
// LDS holds only the 64 node rows (32 KB) => 4 blocks/CU instead of 1.
__global__ __launch_bounds__(256, 4) void linear_tanh(float* __restrict__ inout,
                                                      const float* __restrict__ Wt,
                                                      const float* __restrict__ bias) {
    __shared__ float sAgg[kNPB * kF];   // 32 KB
    __shared__ float sB[kF];

    const int t  = threadIdx.x;
    const int n0 = blockIdx.x * kNPB;

    if (t < kF) sB[t] = bias[t];

    // Stage this block's agg rows (read-before-overwrite => in-place is safe).
    const int rows = min(kNPB, kNodes - n0);
    for (int i = t * 4; i < rows * kF; i += 256 * 4) {
        *reinterpret_cast<float4*>(&sAgg[i]) =
            *reinterpret_cast<const float4*>(inout + (size_t)n0 * kF + i);
    }
    __syncthreads();

    const int tn = t >> 5;        // 0..7  -> node sub-block
    const int to = t & 31;        // 0..31 -> output group, o = to*4 + j
    const int nb = tn * 8;        // 8 nodes per thread

    float acc[8][4];
#pragma unroll
    for (int n = 0; n < 8; ++n)
#pragma unroll
        for (int j = 0; j < 4; ++j) acc[n][j] = 0.0f;

    for (int k = 0; k < kF; k += 4) {
        // wt[i] = (W[4to+0][k+i], ..., W[4to+3][k+i]) — global, L1-hot
        float4 wt[4];
#pragma unroll
        for (int i = 0; i < 4; ++i)
            wt[i] = *reinterpret_cast<const float4*>(Wt + (k + i) * kF + to * 4);
#pragma unroll
        for (int n = 0; n < 8; ++n) {
            float4 av = *reinterpret_cast<const float4*>(&sAgg[(nb + n) * kF + k]);
#pragma unroll
            for (int j = 0; j < 4; ++j) {
                float* wj0 = reinterpret_cast<float*>(&wt[0]);
                float* wj1 = reinterpret_cast<float*>(&wt[1]);
                float* wj2 = reinterpret_cast<float*>(&wt[2]);
                float* wj3 = reinterpret_cast<float*>(&wt[3]);
                acc[n][j] += av.x * wj0[j];
                acc[n][j] += av.y * wj1[j];
                acc[n][j] += av.z * wj2[j];
                acc[n][j] += av.w * wj3[j];
            }
        }
    }

    const float b0 = sB[to * 4 + 0];
    const float b1 = sB[to * 4 + 1];
    const float b2 = sB[to * 4 + 2];
    const float b3 = sB[to * 4 + 3];

#pragma unroll
    for (int n = 0; n < 8; ++n) {
        int node = n0 + nb + n;
        if (node < kNodes) {
            float4 r;
            r.x = 1.0f - 2.0f / (__expf(2.0f * (acc[n][0] + b0)) + 1.0f);
            r.y = 1.0f - 2.0f / (__expf(2.0f * (acc[n][1] + b1)) + 1.0f);
            r.z = 1.0f - 2.0f / (__expf(2.0f * (acc[n][2] + b2)) + 1.0f);
            r.w = 1.0f - 2.0f / (__expf(2.0f * (acc[n][3] + b3)) + 1.0f);
            *reinterpret_cast<float4*>(inout + (size_t)node * kF + to * 4) = r;
        }
    }
}

// ---------------------------------------------------------------------------
extern "C" void kernel_launch(void* const* d_in, const int* in_sizes, int n_in,
                              void* d_out, int out_size, void* d_ws, size_t ws_size,
                              hipStream_t stream) {
    const float* feature = (const float*)d_in[0];
    const float* W       = (const float*)d_in[1];
    const float* b       = (const float*)d_in[2];
    const int*   src     = (const int*)d_in[3];
    const int*   dst     = (const int*)d_in[4];
    float* out = (float*)d_out;

    // workspace layout (16B-aligned chunks)
    char* ws = (char*)d_ws;
    float* Wt     = (float*)(ws);                       //  64 KB
    int*   deg    = (int*)(ws + 65536);                 // 200 KB
    int*   offs   = (int*)(ws + 65536 + 200016);        // 200 KB (+4)
    int*   cursor = (int*)(ws + 65536 + 400032);        // 200 KB
    int*   bucket = (int*)(ws + 65536 + 600048);        // 2.4 MB
    int*   bsum   = (int*)(ws + 65536 + 600048 + 2400000);        // 784 B

    prep<<<kScanB, 256, 0, stream>>>(W, Wt, deg);                     // 50176 threads
    histogram<<<(kEdges + 255) / 256, 256, 0, stream>>>(dst, deg);
    block_sums<<<kScanB, 256, 0, stream>>>(deg, bsum);
    scan_final<<<kScanB, 256, 0, stream>>>(deg, bsum, offs, cursor);
    bucket_fill<<<(kEdges + 255) / 256, 256, 0, stream>>>(src, dst, cursor, bucket);

    // one wave per node: 50000 waves, 4 waves/block
    gather_sum<<<(kNodes + 3) / 4, 256, 0, stream>>>(feature, bucket, offs, out);

    linear_tanh<<<(kNodes + kNPB - 1) / kNPB, 256, 0, stream>>>(out, Wt, b);
}